// Round 10
// baseline (243.872 us; speedup 1.0000x reference)
//
#include <hip/hip_runtime.h>

typedef __bf16 bf16_t;
typedef __bf16 bf16x2 __attribute__((ext_vector_type(2)));
typedef __bf16 bf16x8 __attribute__((ext_vector_type(8)));
typedef float f32x4 __attribute__((ext_vector_type(4)));
typedef unsigned u32;
typedef unsigned u32x4 __attribute__((ext_vector_type(4)));

#define N_PIX 4096
#define CFEAT 256
#define CKEY 32
#define NBATCH 4

#if __has_builtin(__builtin_amdgcn_exp2f)
#define EXP2(x) __builtin_amdgcn_exp2f(x)
#else
#define EXP2(x) exp2f(x)
#endif

static __device__ __forceinline__ f32x4 mfma16(bf16x8 a, bf16x8 b, f32x4 c) {
    return __builtin_amdgcn_mfma_f32_16x16x32_bf16(a, b, c, 0, 0, 0);
}

// pack two f32 -> one dword of 2 bf16 (v_cvt_pk_bf16_f32)
static __device__ __forceinline__ u32 pk2(float lo, float hi) {
    bf16x2 t; t[0] = (bf16_t)lo; t[1] = (bf16_t)hi;
    return __builtin_bit_cast(u32, t);
}

// 4-group transpose step (T12)
static __device__ __forceinline__ void xpose4(u32 &x, u32 &y) {
#if __has_builtin(__builtin_amdgcn_permlane32_swap) && __has_builtin(__builtin_amdgcn_permlane16_swap)
    auto r32 = __builtin_amdgcn_permlane32_swap(x, y, false, false);
    auto r16 = __builtin_amdgcn_permlane16_swap(r32[0], r32[1], false, false);
    x = r16[0]; y = r16[1];
#else
    const int lane = threadIdx.x & 63;
    const int g = lane >> 4, ln = lane & 15;
    const int i0 = ln + ((g & 1) << 5);
    const int i2 = i0 + 16;
    u32 xs0 = (u32)__shfl((int)x, i0), ys0 = (u32)__shfl((int)y, i0);
    u32 xs2 = (u32)__shfl((int)x, i2), ys2 = (u32)__shfl((int)y, i2);
    x = (g < 2) ? xs0 : ys0;
    y = (g < 2) ? xs2 : ys2;
#endif
}

// S^T tile (64 j x 16 i) -> exp2 -> in-register P fragments; l-sum via ones-MFMA.
static __device__ __forceinline__ void softmax_tile(
    const bf16x8 kf[4], bf16x8 qf, bf16x8 ones,
    f32x4 &accsum, bf16x8 &pa0, bf16x8 &pa1)
{
    f32x4 zero = {0.f, 0.f, 0.f, 0.f};
    f32x4 st[4];
#pragma unroll
    for (int jt = 0; jt < 4; ++jt) st[jt] = mfma16(kf[jt], qf, zero);
    float ex[16];
#pragma unroll
    for (int jt = 0; jt < 4; ++jt)
#pragma unroll
        for (int r = 0; r < 4; ++r) ex[jt * 4 + r] = EXP2(st[jt][r]);
    u32 a0 = pk2(ex[0],  ex[1]),  a1 = pk2(ex[2],  ex[3]);
    u32 b0 = pk2(ex[4],  ex[5]),  b1 = pk2(ex[6],  ex[7]);
    u32 c0 = pk2(ex[8],  ex[9]),  c1 = pk2(ex[10], ex[11]);
    u32 d0 = pk2(ex[12], ex[13]), d1 = pk2(ex[14], ex[15]);
    xpose4(a0, b0); xpose4(a1, b1);
    xpose4(c0, d0); xpose4(c1, d1);
    u32x4 w0 = {a0, a1, b0, b1};
    u32x4 w1 = {c0, c1, d0, d1};
    pa0 = __builtin_bit_cast(bf16x8, w0);
    pa1 = __builtin_bit_cast(bf16x8, w1);
    accsum = mfma16(ones, pa0, accsum);
    accsum = mfma16(ones, pa1, accsum);
}

// ---------------------------------------------------------------------------
// proj_kernel (R4-verified, unchanged): Qt/Kt (transposed bf16, Q pre-scaled
// log2e) and V (bf16 [c][n]).
// ---------------------------------------------------------------------------
__global__ __launch_bounds__(256) void proj_kernel(
    const float* __restrict__ Wq, const float* __restrict__ bq, const float* __restrict__ cond,
    const float* __restrict__ Wk, const float* __restrict__ bk, const float* __restrict__ feat,
    const float* __restrict__ Wv, const float* __restrict__ bv,
    bf16_t* __restrict__ Qt, bf16_t* __restrict__ Kt, bf16_t* __restrict__ Vv)
{
    __shared__ __attribute__((aligned(16))) bf16_t T[64][40];  // QK repack, +8 pad
    const int lane = threadIdx.x & 63, wave = threadIdx.x >> 6;
    const int g = lane >> 4, ln = lane & 15;
    const int bid = blockIdx.x;
    f32x4 zero = {0.f, 0.f, 0.f, 0.f};

    if (bid < 512) {
        const bool isK = (bid >= 256);
        const int idx = bid & 255;
        const int xt = idx & 63;
        const int b  = idx >> 6;
        const float* W    = isK ? Wk : Wq;
        const float* bias = isK ? bk : bq;
        const float* X  = (isK ? feat : cond) + (size_t)b * CFEAT * N_PIX;
        bf16_t*      Yt = (isK ? Kt : Qt) + (size_t)b * N_PIX * CKEY;
        const float qscale = isK ? 1.0f : 1.4426950408889634f;  // log2(e) into Q

        const int m_base = (wave & 1) * 16;
        const int n_loc  = (wave >> 1) * 32;
        const int n_base = xt * 64 + n_loc;

        f32x4 acc[2] = {zero, zero};
        for (int k0 = 0; k0 < CFEAT; k0 += 32) {
            bf16x8 a;
            const float* wp = W + (size_t)(m_base + ln) * CFEAT + k0 + g * 8;
#pragma unroll
            for (int j = 0; j < 8; ++j) a[j] = (bf16_t)wp[j];
#pragma unroll
            for (int nt = 0; nt < 2; ++nt) {
                const float* xp = X + (size_t)(k0 + g * 8) * N_PIX + n_base + nt * 16 + ln;
                bf16x8 bfr;
#pragma unroll
                for (int j = 0; j < 8; ++j) bfr[j] = (bf16_t)xp[(size_t)j * N_PIX];
                acc[nt] = mfma16(a, bfr, acc[nt]);
            }
        }
#pragma unroll
        for (int nt = 0; nt < 2; ++nt)
#pragma unroll
            for (int r = 0; r < 4; ++r) {
                const int ck = m_base + g * 4 + r;
                T[n_loc + nt * 16 + ln][ck] = (bf16_t)((acc[nt][r] + bias[ck]) * qscale);
            }
        __syncthreads();
        const int n  = threadIdx.x >> 2;
        const int sg = threadIdx.x & 3;
        bf16x8 row = *(const bf16x8*)&T[n][sg * 8];
        *(bf16x8*)&Yt[(size_t)(xt * 64 + n) * CKEY + sg * 8] = row;
    } else {
        const int idx = bid - 512;
        const int xt = idx & 127;
        const int b  = idx >> 7;
        const int n_base = xt * 32;
        const int c_wave = wave * 64;
        const float* Xb = feat + (size_t)b * CFEAT * N_PIX;
        bf16_t*      Vb = Vv + (size_t)b * CFEAT * N_PIX;

        f32x4 acc[4][2];
#pragma unroll
        for (int mt = 0; mt < 4; ++mt) { acc[mt][0] = zero; acc[mt][1] = zero; }

        for (int k0 = 0; k0 < CFEAT; k0 += 32) {
            bf16x8 bfr[2];
#pragma unroll
            for (int nt = 0; nt < 2; ++nt) {
                const float* xp = Xb + (size_t)(k0 + g * 8) * N_PIX + n_base + nt * 16 + ln;
#pragma unroll
                for (int j = 0; j < 8; ++j) bfr[nt][j] = (bf16_t)xp[(size_t)j * N_PIX];
            }
#pragma unroll
            for (int mt = 0; mt < 4; ++mt) {
                const float* wp = Wv + (size_t)(c_wave + mt * 16 + ln) * CFEAT + k0 + g * 8;
                bf16x8 a;
#pragma unroll
                for (int j = 0; j < 8; ++j) a[j] = (bf16_t)wp[j];
                acc[mt][0] = mfma16(a, bfr[0], acc[mt][0]);
                acc[mt][1] = mfma16(a, bfr[1], acc[mt][1]);
            }
        }
#pragma unroll
        for (int mt = 0; mt < 4; ++mt)
#pragma unroll
            for (int nt = 0; nt < 2; ++nt)
#pragma unroll
                for (int r = 0; r < 4; ++r) {
                    const int m = c_wave + mt * 16 + g * 4 + r;
                    const int n = n_base + nt * 16 + ln;
                    Vb[(size_t)m * N_PIX + n] = (bf16_t)(acc[mt][nt][r] + bv[m]);
                }
    }
}

// ---------------------------------------------------------------------------
// pv v7: V direct global->register — LDS carries ONLY P.
//   R9 analysis: v6 was LDS-BW bound (~168 KB/CU-iter through one 85 B/cyc
//   port ≈ 80% of the iteration wall). The PV A-fragment pattern (row c per
//   ln, 64B contiguous across g) loads fine straight from L2 (same pattern
//   as K). So: no Vlds, no glds16, no vmcnt fences. Per iter:
//     1. pf = ds_read P[n&1] (published by barrier(n-1))
//     2. vfN = V(n+1) frags, 8 global b128 (ping-pong regs, dist-1)
//     3. sm waves: K(n+2) loads; softmax K(n+1) -> PWRITE P[(n+1)&1]
//     4. lgkmcnt(0) + s_barrier (publishes P; no vmem drain — V/K loads
//        stay in flight, compiler waits at use)
//     5. PV(n): 16 MFMA on vfU + pf
//   Role parity flip per block (wave^((f&1)<<1)) pairs sm with pv waves on
//   the same SIMD across co-resident blocks. XCD batch swizzle kept.
// LDS 8.2 KB, grid 512 = 2 blocks/CU (wave-limited, not LDS-limited).
// ---------------------------------------------------------------------------
__global__ __launch_bounds__(256, 2) void pv_kernel(
    const bf16_t* __restrict__ Qt, const bf16_t* __restrict__ Kt,
    const bf16_t* __restrict__ V,
    const float* __restrict__ features, const float* __restrict__ gamma,
    float* __restrict__ out)
{
    __shared__ __attribute__((aligned(16))) bf16_t Plds[2][2048];   // 2 x 4KB
    __shared__ float Llds[32];

    const int lane = threadIdx.x & 63, wave = threadIdx.x >> 6;  // 0..3
    const int g = lane >> 4, ln = lane & 15;
    // XCD-batch swizzle: f%8 = {2b, 2b+1} -> batch b's 128 blocks on 2 XCDs
    const int f = blockIdx.x;
    const int b = (f & 7) >> 1;
    const int i_tile = (f & 1) + 2 * (f >> 3);
    const int i_base = i_tile * 32;
    // role parity flip: odd blocks use waves {2,3} as softmax producers
    const int rw = wave ^ ((f & 1) << 1);
    const bool sm = (rw < 2);
    const int sw = rw & 1;                     // sm index: i-half 0/1

    const bf16_t* Qb = Qt + (size_t)b * N_PIX * CKEY;
    const bf16_t* Kb = Kt + (size_t)b * N_PIX * CKEY;
    const bf16_t* Vb = V + (size_t)b * CFEAT * N_PIX;

    // V fragment base pointers: frag q = ct*2+s -> row c = wave*64+ct*16+ln,
    // col chunk (s*4+g)*8; per-iter offset = j0 (elements).
    const bf16_t* vbase[8];
#pragma unroll
    for (int ct = 0; ct < 4; ++ct)
#pragma unroll
        for (int s = 0; s < 2; ++s)
            vbase[ct * 2 + s] = Vb + (size_t)(wave * 64 + ct * 16 + ln) * N_PIX
                                   + (s * 4 + g) * 8;

#define LOADV(DST, JO)                                                        \
    { _Pragma("unroll") for (int q = 0; q < 8; ++q)                           \
        DST[q] = *(const bf16x8*)(vbase[q] + (JO)); }

#define LOADK(DST, JQ)                                                        \
    { _Pragma("unroll") for (int jt = 0; jt < 4; ++jt)                        \
        DST[jt] = *(const bf16x8*)&Kb[(size_t)((JQ) + jt * 16 + ln) * CKEY + g * 8]; }

    // P [32i][64j], 128-B rows, XOR-8 granule swizzle (v3-proven, 0-conflict)
#define PWRITE(SLOT, PA0, PA1)                                                \
    { const int ir = sw * 16 + ln;                                            \
      char* Pw = (char*)&Plds[SLOT][0] + ir * 128;                            \
      *(bf16x8*)(Pw + ((g)     ^ (ir & 7)) * 16) = PA0;                       \
      *(bf16x8*)(Pw + ((4 + g) ^ (ir & 7)) * 16) = PA1; }

    bf16x8 qf = {};
    if (sm) qf = *(const bf16x8*)&Qb[(size_t)(i_base + sw * 16 + ln) * CKEY + g * 8];

    bf16x8 ones;
#pragma unroll
    for (int j = 0; j < 8; ++j) ones[j] = (bf16_t)1.0f;

    f32x4 zero = {0.f, 0.f, 0.f, 0.f};
    f32x4 acc[4][2];
#pragma unroll
    for (int ct = 0; ct < 4; ++ct) { acc[ct][0] = zero; acc[ct][1] = zero; }
    f32x4 accsum = zero;

    bf16x8 kfA[4], kfB[4];
    bf16x8 vfA[8], vfB[8];

    // -------- prologue: P(0); vfA = V(0); kfA = K(1) ------------------------
    {
        bf16x8 kf0[4];
        if (sm) LOADK(kf0, 0);
        LOADV(vfA, 0);
        if (sm) {
            bf16x8 pa0, pa1;
            softmax_tile(kf0, qf, ones, accsum, pa0, pa1);
            PWRITE(0, pa0, pa1);
            LOADK(kfA, 64);
        }
        asm volatile("s_waitcnt lgkmcnt(0)" ::: "memory");
        __builtin_amdgcn_s_barrier();
        asm volatile("" ::: "memory");
    }

// iter n: pf = P[n&1]; VN = V(n+1); sm: K(n+2) + softmax K(n+1) -> P[(n+1)&1];
// lgkm(0) + barrier (P publish only — vmem stays in flight); PV(n).
#define PV_ITER(NN, VU, VN, KU, KN)                                           \
  {                                                                           \
    const int nn = (NN);                                                      \
    const char* Pr = (const char*)&Plds[nn & 1][0];                           \
    bf16x8 pf[4];                                                             \
    _Pragma("unroll")                                                         \
    for (int it = 0; it < 2; ++it)                                            \
      _Pragma("unroll")                                                       \
      for (int s = 0; s < 2; ++s)                                             \
        pf[it * 2 + s] = *(const bf16x8*)(Pr + (it * 16 + ln) * 128           \
                           + ((s * 4 + g) ^ (ln & 7)) * 16);                  \
    LOADV(VN, (((nn + 1) & 63) * 64));                                        \
    const bool live = (nn < 63);                                              \
    if (sm && live) {                                                         \
      LOADK(KN, ((nn + 2) & 63) * 64);                                        \
      bf16x8 pa0, pa1;                                                        \
      softmax_tile(KU, qf, ones, accsum, pa0, pa1);                           \
      PWRITE((nn + 1) & 1, pa0, pa1);                                         \
    }                                                                         \
    asm volatile("s_waitcnt lgkmcnt(0)" ::: "memory");                        \
    __builtin_amdgcn_s_barrier();                                             \
    asm volatile("" ::: "memory");                                            \
    __builtin_amdgcn_s_setprio(1);                                            \
    _Pragma("unroll")                                                         \
    for (int ct = 0; ct < 4; ++ct)                                            \
      _Pragma("unroll")                                                       \
      for (int it = 0; it < 2; ++it) {                                        \
        acc[ct][it] = mfma16(VU[ct * 2 + 0], pf[it * 2 + 0], acc[ct][it]);    \
        acc[ct][it] = mfma16(VU[ct * 2 + 1], pf[it * 2 + 1], acc[ct][it]);    \
      }                                                                       \
    __builtin_amdgcn_s_setprio(0);                                            \
  }

    for (int n2 = 0; n2 < 32; ++n2) {
        PV_ITER(2 * n2,     vfA, vfB, kfA, kfB);
        PV_ITER(2 * n2 + 1, vfB, vfA, kfB, kfA);
    }
#undef PV_ITER

    // publish l_i (accsum rows identical = full j-sum for i = ln)
    if (sm && g == 0) Llds[sw * 16 + ln] = accsum[0];
    __syncthreads();
    const float gam = gamma[0];
    float sc2[2];
#pragma unroll
    for (int it = 0; it < 2; ++it) sc2[it] = gam / Llds[it * 16 + ln];

#pragma unroll
    for (int ct = 0; ct < 4; ++ct)
#pragma unroll
        for (int it = 0; it < 2; ++it)
#pragma unroll
            for (int r = 0; r < 4; ++r) {
                const int c = wave * 64 + ct * 16 + g * 4 + r;
                const int i = i_base + it * 16 + ln;
                const size_t idx = ((size_t)b * CFEAT + c) * N_PIX + i;
                out[idx] = sc2[it] * acc[ct][it][r] + features[idx];
            }
#undef LOADV
#undef LOADK
#undef PWRITE
}

// ---------------------------------------------------------------------------
extern "C" void kernel_launch(void* const* d_in, const int* in_sizes, int n_in,
                              void* d_out, int out_size, void* d_ws, size_t ws_size,
                              hipStream_t stream) {
    const float* features   = (const float*)d_in[0];
    const float* conditions = (const float*)d_in[1];
    const float* Wq  = (const float*)d_in[2];
    const float* bq  = (const float*)d_in[3];
    const float* Wk  = (const float*)d_in[4];
    const float* bk  = (const float*)d_in[5];
    const float* Wv  = (const float*)d_in[6];
    const float* bv  = (const float*)d_in[7];
    const float* gam = (const float*)d_in[8];
    float* out = (float*)d_out;

    // ws (bf16): Qt 1MB | Kt 1MB | V 8MB
    bf16_t* Qt = (bf16_t*)d_ws;
    bf16_t* Kt = Qt + (size_t)NBATCH * N_PIX * CKEY;
    bf16_t* Vw = Kt + (size_t)NBATCH * N_PIX * CKEY;

    proj_kernel<<<dim3(1024, 1, 1), 256, 0, stream>>>(
        Wq, bq, conditions, Wk, bk, features, Wv, bv, Qt, Kt, Vw);
    pv_kernel<<<dim3(512, 1, 1), 256, 0, stream>>>(
        Qt, Kt, Vw, features, gam, out);
}

// Round 12
// 170.766 us; speedup vs baseline: 1.4281x; 1.4281x over previous
//
#include <hip/hip_runtime.h>

typedef __bf16 bf16_t;
typedef __bf16 bf16x2 __attribute__((ext_vector_type(2)));
typedef __bf16 bf16x8 __attribute__((ext_vector_type(8)));
typedef float f32x4 __attribute__((ext_vector_type(4)));
typedef unsigned u32;
typedef unsigned u32x4 __attribute__((ext_vector_type(4)));

#define N_PIX 4096
#define CFEAT 256
#define CKEY 32
#define NBATCH 4

#if __has_builtin(__builtin_amdgcn_exp2f)
#define EXP2(x) __builtin_amdgcn_exp2f(x)
#else
#define EXP2(x) exp2f(x)
#endif

static __device__ __forceinline__ f32x4 mfma16(bf16x8 a, bf16x8 b, f32x4 c) {
    return __builtin_amdgcn_mfma_f32_16x16x32_bf16(a, b, c, 0, 0, 0);
}

// async global->LDS, 16B per lane; LDS dest = wave-uniform base + lane*16
static __device__ __forceinline__ void glds16(const void* g, void* l) {
    __builtin_amdgcn_global_load_lds(
        (const __attribute__((address_space(1))) void*)g,
        (__attribute__((address_space(3))) void*)l, 16, 0, 0);
}

// pack two f32 -> one dword of 2 bf16 (v_cvt_pk_bf16_f32, RNE — same as scalar cast)
static __device__ __forceinline__ u32 pk2(float lo, float hi) {
    bf16x2 t; t[0] = (bf16_t)lo; t[1] = (bf16_t)hi;
    return __builtin_bit_cast(u32, t);
}

// cast 8 consecutive f32 (two float4 loads) -> bf16x8 fragment (R5-verified)
static __device__ __forceinline__ bf16x8 cast8(const float* p) {
    f32x4 lo = *(const f32x4*)p;
    f32x4 hi = *(const f32x4*)(p + 4);
    u32x4 w = {pk2(lo[0], lo[1]), pk2(lo[2], lo[3]),
               pk2(hi[0], hi[1]), pk2(hi[2], hi[3])};
    return __builtin_bit_cast(bf16x8, w);
}

// 4-group transpose step (T12)
static __device__ __forceinline__ void xpose4(u32 &x, u32 &y) {
#if __has_builtin(__builtin_amdgcn_permlane32_swap) && __has_builtin(__builtin_amdgcn_permlane16_swap)
    auto r32 = __builtin_amdgcn_permlane32_swap(x, y, false, false);
    auto r16 = __builtin_amdgcn_permlane16_swap(r32[0], r32[1], false, false);
    x = r16[0]; y = r16[1];
#else
    const int lane = threadIdx.x & 63;
    const int g = lane >> 4, ln = lane & 15;
    const int i0 = ln + ((g & 1) << 5);
    const int i2 = i0 + 16;
    u32 xs0 = (u32)__shfl((int)x, i0), ys0 = (u32)__shfl((int)y, i0);
    u32 xs2 = (u32)__shfl((int)x, i2), ys2 = (u32)__shfl((int)y, i2);
    x = (g < 2) ? xs0 : ys0;
    y = (g < 2) ? xs2 : ys2;
#endif
}

// S^T tile (64 j x 16 i) -> exp2 -> in-register P fragments; l-sum via ones-MFMA.
static __device__ __forceinline__ void softmax_tile(
    const bf16x8 kf[4], bf16x8 qf, bf16x8 ones,
    f32x4 &accsum, bf16x8 &pa0, bf16x8 &pa1)
{
    f32x4 zero = {0.f, 0.f, 0.f, 0.f};
    f32x4 st[4];
#pragma unroll
    for (int jt = 0; jt < 4; ++jt) st[jt] = mfma16(kf[jt], qf, zero);
    float ex[16];
#pragma unroll
    for (int jt = 0; jt < 4; ++jt)
#pragma unroll
        for (int r = 0; r < 4; ++r) ex[jt * 4 + r] = EXP2(st[jt][r]);
    u32 a0 = pk2(ex[0],  ex[1]),  a1 = pk2(ex[2],  ex[3]);
    u32 b0 = pk2(ex[4],  ex[5]),  b1 = pk2(ex[6],  ex[7]);
    u32 c0 = pk2(ex[8],  ex[9]),  c1 = pk2(ex[10], ex[11]);
    u32 d0 = pk2(ex[12], ex[13]), d1 = pk2(ex[14], ex[15]);
    xpose4(a0, b0); xpose4(a1, b1);
    xpose4(c0, d0); xpose4(c1, d1);
    u32x4 w0 = {a0, a1, b0, b1};
    u32x4 w1 = {c0, c1, d0, d1};
    pa0 = __builtin_bit_cast(bf16x8, w0);
    pa1 = __builtin_bit_cast(bf16x8, w1);
    accsum = mfma16(ones, pa0, accsum);
    accsum = mfma16(ones, pa1, accsum);
}

// ---------------------------------------------------------------------------
// proj_kernel: R4-verified structure + cast8 W-loads (kills the 64-lane
// 1KB-stride scalar W scatter — 4x fewer load instrs and transactions).
// X loads stay scalar (4-row x 64B coalesced — acceptable).
// ---------------------------------------------------------------------------
__global__ __launch_bounds__(256) void proj_kernel(
    const float* __restrict__ Wq, const float* __restrict__ bq, const float* __restrict__ cond,
    const float* __restrict__ Wk, const float* __restrict__ bk, const float* __restrict__ feat,
    const float* __restrict__ Wv, const float* __restrict__ bv,
    bf16_t* __restrict__ Qt, bf16_t* __restrict__ Kt, bf16_t* __restrict__ Vv)
{
    __shared__ __attribute__((aligned(16))) bf16_t T[64][40];  // QK repack, +8 pad
    const int lane = threadIdx.x & 63, wave = threadIdx.x >> 6;
    const int g = lane >> 4, ln = lane & 15;
    const int bid = blockIdx.x;
    f32x4 zero = {0.f, 0.f, 0.f, 0.f};

    if (bid < 512) {
        const bool isK = (bid >= 256);
        const int idx = bid & 255;
        const int xt = idx & 63;
        const int b  = idx >> 6;
        const float* W    = isK ? Wk : Wq;
        const float* bias = isK ? bk : bq;
        const float* X  = (isK ? feat : cond) + (size_t)b * CFEAT * N_PIX;
        bf16_t*      Yt = (isK ? Kt : Qt) + (size_t)b * N_PIX * CKEY;
        const float qscale = isK ? 1.0f : 1.4426950408889634f;  // log2(e) into Q

        const int m_base = (wave & 1) * 16;
        const int n_loc  = (wave >> 1) * 32;
        const int n_base = xt * 64 + n_loc;

        f32x4 acc[2] = {zero, zero};
        for (int k0 = 0; k0 < CFEAT; k0 += 32) {
            bf16x8 a = cast8(W + (size_t)(m_base + ln) * CFEAT + k0 + g * 8);
#pragma unroll
            for (int nt = 0; nt < 2; ++nt) {
                const float* xp = X + (size_t)(k0 + g * 8) * N_PIX + n_base + nt * 16 + ln;
                bf16x8 bfr;
#pragma unroll
                for (int j = 0; j < 8; ++j) bfr[j] = (bf16_t)xp[(size_t)j * N_PIX];
                acc[nt] = mfma16(a, bfr, acc[nt]);
            }
        }
#pragma unroll
        for (int nt = 0; nt < 2; ++nt)
#pragma unroll
            for (int r = 0; r < 4; ++r) {
                const int ck = m_base + g * 4 + r;
                T[n_loc + nt * 16 + ln][ck] = (bf16_t)((acc[nt][r] + bias[ck]) * qscale);
            }
        __syncthreads();
        const int n  = threadIdx.x >> 2;
        const int sg = threadIdx.x & 3;
        bf16x8 row = *(const bf16x8*)&T[n][sg * 8];
        *(bf16x8*)&Yt[(size_t)(xt * 64 + n) * CKEY + sg * 8] = row;
    } else {
        const int idx = bid - 512;
        const int xt = idx & 127;
        const int b  = idx >> 7;
        const int n_base = xt * 32;
        const int c_wave = wave * 64;
        const float* Xb = feat + (size_t)b * CFEAT * N_PIX;
        bf16_t*      Vb = Vv + (size_t)b * CFEAT * N_PIX;

        f32x4 acc[4][2];
#pragma unroll
        for (int mt = 0; mt < 4; ++mt) { acc[mt][0] = zero; acc[mt][1] = zero; }

        for (int k0 = 0; k0 < CFEAT; k0 += 32) {
            bf16x8 bfr[2];
#pragma unroll
            for (int nt = 0; nt < 2; ++nt) {
                const float* xp = Xb + (size_t)(k0 + g * 8) * N_PIX + n_base + nt * 16 + ln;
#pragma unroll
                for (int j = 0; j < 8; ++j) bfr[nt][j] = (bf16_t)xp[(size_t)j * N_PIX];
            }
#pragma unroll
            for (int mt = 0; mt < 4; ++mt) {
                bf16x8 a = cast8(Wv + (size_t)(c_wave + mt * 16 + ln) * CFEAT + k0 + g * 8);
                acc[mt][0] = mfma16(a, bfr[0], acc[mt][0]);
                acc[mt][1] = mfma16(a, bfr[1], acc[mt][1]);
            }
        }
#pragma unroll
        for (int mt = 0; mt < 4; ++mt)
#pragma unroll
            for (int nt = 0; nt < 2; ++nt)
#pragma unroll
                for (int r = 0; r < 4; ++r) {
                    const int m = c_wave + mt * 16 + g * 4 + r;
                    const int n = n_base + nt * 16 + ln;
                    Vb[(size_t)m * N_PIX + n] = (bf16_t)(acc[mt][nt][r] + bv[m]);
                }
    }
}

// ---------------------------------------------------------------------------
// pv v6 (R9-verified, 66.5 us — byte-identical revert): 4-wave producer/
// consumer, j=64, ring-2 V with stage-distance-2 (fence never drains a fresh
// DMA), XOR-8 swizzles (0 bank conflicts), XCD batch swizzle, 2 blocks/CU.
// R10 lesson: V MUST go through glds16 staging — direct global fragments
// scatter 16 rows/instruction and TA-serialize (141 us).
// ---------------------------------------------------------------------------
__global__ __launch_bounds__(256, 2) void pv_kernel(
    const bf16_t* __restrict__ Qt, const bf16_t* __restrict__ Kt,
    const bf16_t* __restrict__ V,
    const float* __restrict__ features, const float* __restrict__ gamma,
    float* __restrict__ out)
{
    __shared__ __attribute__((aligned(16))) bf16_t Vlds[2][16384];  // 2 x 32KB
    __shared__ __attribute__((aligned(16))) bf16_t Plds[2][2048];   // 2 x 4KB
    __shared__ float Llds[32];

    const int lane = threadIdx.x & 63, wave = threadIdx.x >> 6;  // 0..3
    const int g = lane >> 4, ln = lane & 15;
    // XCD-batch swizzle: f%8 = {2b, 2b+1} -> batch b's 128 blocks on 2 XCDs
    const int f = blockIdx.x;
    const int b = (f & 7) >> 1;
    const int i_tile = (f & 1) + 2 * (f >> 3);
    const int i_base = i_tile * 32;
    const bool sm = (wave < 2);

    const bf16_t* Qb = Qt + (size_t)b * N_PIX * CKEY;
    const bf16_t* Kb = Kt + (size_t)b * N_PIX * CKEY;
    const bf16_t* Vb = V + (size_t)b * CFEAT * N_PIX;

    // staging map (v3-proven): slot s in [0,2048): c = s>>3, jslot = (s&7)^(c&7)
    const int nq = sm ? 4 : 12;
    const int sbase = sm ? (wave * 64 + lane) : (512 + (wave - 2) * 64 + lane);
    const bf16_t* vgp[12];
#pragma unroll
    for (int q = 0; q < 12; ++q) {
        const int s = sbase + (q < nq ? q : 0) * 128;
        const int sc = s >> 3, sj = (s & 7) ^ (sc & 7);
        vgp[q] = Vb + (size_t)sc * N_PIX + sj * 8;
    }

#define STAGE(BUF, JOFF)                                                      \
    if (sm) {                                                                 \
        _Pragma("unroll") for (int q = 0; q < 4; ++q)                         \
            glds16(vgp[q] + (JOFF), &Vlds[BUF][(sbase + q * 128) * 8]);       \
    } else {                                                                  \
        _Pragma("unroll") for (int q = 0; q < 12; ++q)                        \
            glds16(vgp[q] + (JOFF), &Vlds[BUF][(sbase + q * 128) * 8]);       \
    }

#define LOADK(DST, JQ)                                                        \
    { _Pragma("unroll") for (int jt = 0; jt < 4; ++jt)                        \
        DST[jt] = *(const bf16x8*)&Kb[(size_t)((JQ) + jt * 16 + ln) * CKEY + g * 8]; }

    // P [32i][64j], 128-B rows, XOR-8 granule swizzle (v3-proven)
#define PWRITE(SLOT, PA0, PA1)                                                \
    { const int ir = wave * 16 + ln;                                          \
      char* Pw = (char*)&Plds[SLOT][0] + ir * 128;                            \
      *(bf16x8*)(Pw + ((g)     ^ (ir & 7)) * 16) = PA0;                       \
      *(bf16x8*)(Pw + ((4 + g) ^ (ir & 7)) * 16) = PA1; }

    bf16x8 qf = {};
    if (sm) qf = *(const bf16x8*)&Qb[(size_t)(i_base + wave * 16 + ln) * CKEY + g * 8];

    bf16x8 ones;
#pragma unroll
    for (int j = 0; j < 8; ++j) ones[j] = (bf16_t)1.0f;

    f32x4 zero = {0.f, 0.f, 0.f, 0.f};
    f32x4 acc[4][2];
#pragma unroll
    for (int ct = 0; ct < 4; ++ct) { acc[ct][0] = zero; acc[ct][1] = zero; }
    f32x4 accsum = zero;

    bf16x8 kfA[4], kfB[4];

    // -------- prologue: stage V(0)->buf0, V(1)->buf1; P(0); kfA = K(1) ------
    {
        bf16x8 kf0[4];
        if (sm) LOADK(kf0, 0);
        asm volatile("" ::: "memory");
        STAGE(0, 0);
        STAGE(1, 64);
        if (sm) {
            bf16x8 pa0, pa1;
            softmax_tile(kf0, qf, ones, accsum, pa0, pa1);
            PWRITE(0, pa0, pa1);
            LOADK(kfA, 64);
        }
        asm volatile("s_waitcnt vmcnt(0)" ::: "memory");
        asm volatile("s_waitcnt lgkmcnt(0)" ::: "memory");
        __builtin_amdgcn_s_barrier();
        asm volatile("" ::: "memory");
    }

// iter n: ds_read V(n)+P(n) frags from buf[n&1]; sm: K(n+2) + softmax
// K(n+1) -> P(n+1); lgkm(0) (read-before-overwrite guard + P publish);
// stage V(n+2) into buf[n&1]; fence sm vmcnt(8) / pv vmcnt(12); barrier;
// PV(n) MFMAs.
#define PV_ITER(NN, KU, KN)                                                   \
  {                                                                           \
    const int nn = (NN);                                                      \
    const bf16_t* Vt = &Vlds[nn & 1][0];                                      \
    bf16x8 vf[8];                                                             \
    _Pragma("unroll")                                                         \
    for (int ct = 0; ct < 4; ++ct)                                            \
      _Pragma("unroll")                                                       \
      for (int s = 0; s < 2; ++s) {                                           \
        const int c = wave * 64 + ct * 16 + ln;                               \
        vf[ct * 2 + s] = *(const bf16x8*)&Vt[(c * 8 + ((s * 4 + g) ^ (c & 7))) * 8]; \
      }                                                                       \
    const char* Pr = (const char*)&Plds[nn & 1][0];                           \
    bf16x8 pf[4];                                                             \
    _Pragma("unroll")                                                         \
    for (int it = 0; it < 2; ++it)                                            \
      _Pragma("unroll")                                                       \
      for (int s = 0; s < 2; ++s)                                             \
        pf[it * 2 + s] = *(const bf16x8*)(Pr + (it * 16 + ln) * 128           \
                           + ((s * 4 + g) ^ (ln & 7)) * 16);                  \
    const bool live = (nn < 63);                                              \
    if (sm && live) {                                                         \
      LOADK(KN, ((nn + 2) & 63) * 64);                                        \
      bf16x8 pa0, pa1;                                                        \
      softmax_tile(KU, qf, ones, accsum, pa0, pa1);                           \
      PWRITE((nn + 1) & 1, pa0, pa1);                                         \
    }                                                                         \
    asm volatile("s_waitcnt lgkmcnt(0)" ::: "memory");                        \
    STAGE((nn) & 1, (((nn + 2) & 63) * 64));                                  \
    if (sm) { asm volatile("s_waitcnt vmcnt(8)" ::: "memory"); }              \
    else    { asm volatile("s_waitcnt vmcnt(12)" ::: "memory"); }             \
    __builtin_amdgcn_s_barrier();                                             \
    asm volatile("" ::: "memory");                                            \
    __builtin_amdgcn_s_setprio(1);                                            \
    _Pragma("unroll")                                                         \
    for (int ct = 0; ct < 4; ++ct)                                            \
      _Pragma("unroll")                                                       \
      for (int it = 0; it < 2; ++it) {                                        \
        acc[ct][it] = mfma16(vf[ct * 2 + 0], pf[it * 2 + 0], acc[ct][it]);    \
        acc[ct][it] = mfma16(vf[ct * 2 + 1], pf[it * 2 + 1], acc[ct][it]);    \
      }                                                                       \
    __builtin_amdgcn_s_setprio(0);                                            \
  }

    for (int n2 = 0; n2 < 32; ++n2) {
        PV_ITER(2 * n2,     kfA, kfB);
        PV_ITER(2 * n2 + 1, kfB, kfA);
    }
#undef PV_ITER

    // publish l_i (accsum rows identical = full 64-tile j-sum for i = ln)
    if (sm && g == 0) Llds[wave * 16 + ln] = accsum[0];
    __syncthreads();
    const float gam = gamma[0];
    float sc2[2];
#pragma unroll
    for (int it = 0; it < 2; ++it) sc2[it] = gam / Llds[it * 16 + ln];

#pragma unroll
    for (int ct = 0; ct < 4; ++ct)
#pragma unroll
        for (int it = 0; it < 2; ++it)
#pragma unroll
            for (int r = 0; r < 4; ++r) {
                const int c = wave * 64 + ct * 16 + g * 4 + r;
                const int i = i_base + it * 16 + ln;
                const size_t idx = ((size_t)b * CFEAT + c) * N_PIX + i;
                out[idx] = sc2[it] * acc[ct][it][r] + features[idx];
            }
#undef STAGE
#undef LOADK
#undef PWRITE
}

// ---------------------------------------------------------------------------
extern "C" void kernel_launch(void* const* d_in, const int* in_sizes, int n_in,
                              void* d_out, int out_size, void* d_ws, size_t ws_size,
                              hipStream_t stream) {
    const float* features   = (const float*)d_in[0];
    const float* conditions = (const float*)d_in[1];
    const float* Wq  = (const float*)d_in[2];
    const float* bq  = (const float*)d_in[3];
    const float* Wk  = (const float*)d_in[4];
    const float* bk  = (const float*)d_in[5];
    const float* Wv  = (const float*)d_in[6];
    const float* bv  = (const float*)d_in[7];
    const float* gam = (const float*)d_in[8];
    float* out = (float*)d_out;

    // ws (bf16): Qt 1MB | Kt 1MB | V 8MB
    bf16_t* Qt = (bf16_t*)d_ws;
    bf16_t* Kt = Qt + (size_t)NBATCH * N_PIX * CKEY;
    bf16_t* Vw = Kt + (size_t)NBATCH * N_PIX * CKEY;

    proj_kernel<<<dim3(1024, 1, 1), 256, 0, stream>>>(
        Wq, bq, conditions, Wk, bk, features, Wv, bv, Qt, Kt, Vw);
    pv_kernel<<<dim3(512, 1, 1), 256, 0, stream>>>(
        Qt, Kt, Vw, features, gam, out);
}